// Round 2
// baseline (240.971 us; speedup 1.0000x reference)
//
#include <hip/hip_runtime.h>

#define N_DENSE 13
#define N_FIELDS 26
#define PER_FIELD 100000
#define FEATURE_NUM (N_FIELDS * PER_FIELD + N_DENSE)  // 2,600,013
#define K_DIM 16
#define BATCH 4096

// One 64-lane wave per batch row.
// lane = fsub*16 + k  (fsub in 0..3, k in 0..15)
// Each lane gathers V[k, idx(f)] for f = fsub, fsub+4, ... and accumulates
// e (sum of latent), sq (sum of squares), lin (first-order, k==0 lanes only).
__global__ __launch_bounds__(256) void fm_layer_kernel(
    const float* __restrict__ dense,   // [B, 13]
    const int*   __restrict__ sparse,  // [B, 26]
    const float* __restrict__ w0,      // [1]
    const float* __restrict__ w,       // [FEATURE_NUM] (second dim is 1)
    const float* __restrict__ V,       // [16, FEATURE_NUM] row-major
    float*       __restrict__ out)     // [B]
{
    const int wave_in_block = threadIdx.x >> 6;
    const int lane = threadIdx.x & 63;
    const int b = blockIdx.x * (blockDim.x >> 6) + wave_in_block;
    if (b >= BATCH) return;

    const int k    = lane & 15;
    const int fsub = lane >> 4;   // 0..3

    const size_t vrow = (size_t)k * FEATURE_NUM;

    // ---- sparse gather indices: issue index loads first ----
    int gidx[7];
    #pragma unroll
    for (int i = 0; i < 7; ++i) {
        int f = fsub + 4 * i;
        if (f < N_FIELDS) {
            gidx[i] = N_DENSE + f * PER_FIELD + sparse[b * N_FIELDS + f];
        } else {
            gidx[i] = -1;
        }
    }

    float e = 0.f, sq = 0.f, lin = 0.f;

    // ---- dense part: lane handles d = fsub, fsub+4, ... (<13) ----
    #pragma unroll
    for (int d = fsub; d < N_DENSE; d += 4) {
        float x = dense[b * N_DENSE + d];
        float v = V[vrow + d];
        e  += x * v;
        sq += (x * x) * (v * v);
        if (k == 0) lin += x * w[d];
    }

    // ---- sparse part: gathers ----
    #pragma unroll
    for (int i = 0; i < 7; ++i) {
        if (gidx[i] >= 0) {
            size_t g = (size_t)gidx[i];
            float v = V[vrow + g];
            e  += v;
            sq += v * v;
            if (k == 0) lin += w[g];
        }
    }

    // ---- reduce e, sq across the 4 field-subset groups (same k) ----
    e  += __shfl_xor(e, 16, 64);
    e  += __shfl_xor(e, 32, 64);
    sq += __shfl_xor(sq, 16, 64);
    sq += __shfl_xor(sq, 32, 64);

    float t = e * e - sq;   // per-k term, replicated across the 4 groups

    // ---- sum t over k (within each 16-lane group), and lin over all 64 ----
    #pragma unroll
    for (int m = 1; m <= 8; m <<= 1) {
        t   += __shfl_xor(t, m, 64);
        lin += __shfl_xor(lin, m, 64);
    }
    lin += __shfl_xor(lin, 16, 64);
    lin += __shfl_xor(lin, 32, 64);

    if (lane == 0) {
        out[b] = w0[0] + lin + 0.5f * t;
    }
}

extern "C" void kernel_launch(void* const* d_in, const int* in_sizes, int n_in,
                              void* d_out, int out_size, void* d_ws, size_t ws_size,
                              hipStream_t stream) {
    const float* dense  = (const float*)d_in[0];
    const int*   sparse = (const int*)d_in[1];
    const float* w0     = (const float*)d_in[2];
    const float* w      = (const float*)d_in[3];
    const float* V      = (const float*)d_in[4];
    float* out = (float*)d_out;

    const int waves_per_block = 4;             // 256 threads
    const int blocks = BATCH / waves_per_block; // 1024
    fm_layer_kernel<<<blocks, 256, 0, stream>>>(dense, sparse, w0, w, V, out);
}